// Round 6
// baseline (267.338 us; speedup 1.0000x reference)
//
#include <hip/hip_runtime.h>
#include <math.h>

// dims
#define B_   64
#define N1_  1152
#define P_   8
#define N2_  128
#define D_   16

#define NSPLIT 24                      // i-splits for k1/k3c partials
#define CHUNK  (N1_ / NSPLIT)          // 48 i per chunk
#define NIB    (CHUNK / 4)             // 12 i-blocks of 4

typedef __attribute__((ext_vector_type(8))) short bf16x8;
typedef __attribute__((ext_vector_type(4))) float f32x4;

// split 8 fp32 into hi/lo bf16 fragments (hi = truncate, lo = bf16(w - hi))
__device__ inline void split_frag(float4 a0, float4 a1, bf16x8& hi, bf16x8& lo)
{
    float w[8] = {a0.x, a0.y, a0.z, a0.w, a1.x, a1.y, a1.z, a1.w};
#pragma unroll
    for (int j = 0; j < 8; ++j) {
        unsigned ub = __float_as_uint(w[j]);
        hi[j] = (short)(ub >> 16);
        float hif = __uint_as_float(ub & 0xffff0000u);
        float r = w[j] - hif;
        lo[j] = (short)(__float_as_uint(r) >> 16);
    }
}

// ---------------------------------------------------------------------------
// K1 (MFMA, validated r4): s0p[isp][b][n][d] = sum_{i in chunk, p} W[i,n,d,p]*x[b,i,p]
// MFMA 16x16x32: M=d, N=b-tile(16), K=4i x 8p. 4 waves = 4 b-tiles.
// grid (32 n-grp, NSPLIT).
// ---------------------------------------------------------------------------
__global__ __launch_bounds__(256) void k1_s0_mfma(const float* __restrict__ x,
                                                  const float* __restrict__ W,
                                                  float* __restrict__ s0p)
{
    const int tid   = threadIdx.x;
    const int lane  = tid & 63;
    const int wv    = tid >> 6;
    const int col   = lane & 15;
    const int quad  = lane >> 4;
    const int b     = wv * 16 + col;
    const int nbase = blockIdx.x * 4;
    const int isp   = blockIdx.y;
    const int ibase = isp * CHUNK;

    f32x4 acc[4];
#pragma unroll
    for (int nn = 0; nn < 4; ++nn) acc[nn] = (f32x4){0.f, 0.f, 0.f, 0.f};

    const float* xlane = x + ((size_t)b * N1_ + ibase + quad) * P_;

    for (int ib = 0; ib < NIB; ++ib) {
        const int i0 = ibase + ib * 4;
        float4 xa = *(const float4*)(xlane);
        float4 xb = *(const float4*)(xlane + 4);
        xlane += 4 * P_;
        bf16x8 bhi, blo;
        split_frag(xa, xb, bhi, blo);
#pragma unroll
        for (int nn = 0; nn < 4; ++nn) {
            const float* wp = W + (((size_t)(i0 + quad) * N2_ + nbase + nn) * D_ + col) * P_;
            float4 wa = *(const float4*)wp;
            float4 wb = *(const float4*)(wp + 4);
            bf16x8 ahi, alo;
            split_frag(wa, wb, ahi, alo);
            acc[nn] = __builtin_amdgcn_mfma_f32_16x16x32_bf16(ahi, bhi, acc[nn], 0, 0, 0);
            acc[nn] = __builtin_amdgcn_mfma_f32_16x16x32_bf16(ahi, blo, acc[nn], 0, 0, 0);
            acc[nn] = __builtin_amdgcn_mfma_f32_16x16x32_bf16(alo, bhi, acc[nn], 0, 0, 0);
        }
    }
#pragma unroll
    for (int nn = 0; nn < 4; ++nn) {
        float4 v = make_float4(acc[nn][0], acc[nn][1], acc[nn][2], acc[nn][3]);
        *(float4*)(s0p + (size_t)isp * (B_ * N2_ * D_) + (size_t)b * (N2_ * D_)
                   + (nbase + nn) * D_ + quad * 4) = v;
    }
}

// ---------------------------------------------------------------------------
// K2/K4: reduce nsplit partials, scale, squash over d (16), write v.
// ---------------------------------------------------------------------------
__global__ __launch_bounds__(256) void k2_squash(const float* __restrict__ spart,
                                                 float* __restrict__ vout,
                                                 float scale, int nsplit)
{
    int idx = blockIdx.x * 256 + threadIdx.x;   // 0 .. 131071
    float s = 0.f;
    for (int sp = 0; sp < nsplit; ++sp)
        s += spart[(size_t)sp * (B_ * N2_ * D_) + idx];
    s *= scale;
    float sq = s * s;
    sq += __shfl_xor(sq, 1);
    sq += __shfl_xor(sq, 2);
    sq += __shfl_xor(sq, 4);
    sq += __shfl_xor(sq, 8);
    float norm = sqrtf(sq + 1.1920929e-7f);
    vout[idx] = (sq / (1.f + sq)) * (s / norm);
}

// ---------------------------------------------------------------------------
// K3AB (fused raw + softmax): one block per i.
// Stage W[i] (4096 float4, 64 KB) into LDS with layout Wl4[q][col],
// col = (n+q)&127 rotation swizzle:
//   - staging: coalesced global f4 reads (f = t+256k, n=f>>5, q=f&31);
//     LDS writes are 4-way conflicts on only 16 instrs (negligible).
//   - compute: ds_read_b128 of Wl4[2d][(n+2d)&127], per-lane n varies ->
//     stride-1-float4 bank pattern = conflict-free.
// Thread t: ng=t&31 (n = ng+32*ln), bg=t>>5 -> 8 b.
// out[ln][bb] = sum_d v0[b,n,d] * (sum_p W[i,n,d,p]*x[b,i,p])  (all fp32)
// softmax over n in-registers (4 local x 32 lanes, shfl bits 0-4),
// writes c_t[i][n][b] (layout k3c's B-side loads coalesced).
// ---------------------------------------------------------------------------
__global__ __launch_bounds__(256) void k3ab(const float* __restrict__ x,
                                            const float* __restrict__ W,
                                            const float* __restrict__ v0,
                                            float* __restrict__ c_t)
{
    __shared__ float4 Wl4[32 * 128];   // [q][col], exactly 64 KB
    const int i  = blockIdx.x;
    const int t  = threadIdx.x;
    const int ng = t & 31;
    const int bg = t >> 5;
    const int b0 = bg * 8;

    const float4* Wg = (const float4*)(W + (size_t)i * (N2_ * D_ * P_));
#pragma unroll
    for (int k = 0; k < 16; ++k) {
        const int f = t + 256 * k;          // 0..4095
        const int n = f >> 5, q = f & 31;
        Wl4[q * 128 + ((n + q) & 127)] = Wg[f];
    }

    float xr[8][8];
#pragma unroll
    for (int bb = 0; bb < 8; ++bb) {
        const float* xp = x + ((size_t)(b0 + bb) * N1_ + i) * P_;
        float4 a0 = *(const float4*)xp;
        float4 a1 = *(const float4*)(xp + 4);
        xr[bb][0] = a0.x; xr[bb][1] = a0.y; xr[bb][2] = a0.z; xr[bb][3] = a0.w;
        xr[bb][4] = a1.x; xr[bb][5] = a1.y; xr[bb][6] = a1.z; xr[bb][7] = a1.w;
    }
    __syncthreads();

    float out[4][8];
#pragma unroll
    for (int ln = 0; ln < 4; ++ln)
#pragma unroll
        for (int bb = 0; bb < 8; ++bb) out[ln][bb] = 0.f;

#pragma unroll
    for (int ln = 0; ln < 4; ++ln) {
        const int n = ng + 32 * ln;
#pragma unroll 1
        for (int qq = 0; qq < 4; ++qq) {        // d in blocks of 4
            float4 vq[8];
#pragma unroll
            for (int bb = 0; bb < 8; ++bb)
                vq[bb] = *(const float4*)(v0 + (size_t)(b0 + bb) * (N2_ * D_)
                                          + n * D_ + qq * 4);
#pragma unroll
            for (int dd = 0; dd < 4; ++dd) {
                const int d  = qq * 4 + dd;
                const int qA = 2 * d, qB = 2 * d + 1;
                float4 wlo = Wl4[qA * 128 + ((n + qA) & 127)];
                float4 whi = Wl4[qB * 128 + ((n + qB) & 127)];
#pragma unroll
                for (int bb = 0; bb < 8; ++bb) {
                    float pd = wlo.x * xr[bb][0] + wlo.y * xr[bb][1]
                             + wlo.z * xr[bb][2] + wlo.w * xr[bb][3]
                             + whi.x * xr[bb][4] + whi.y * xr[bb][5]
                             + whi.z * xr[bb][6] + whi.w * xr[bb][7];
                    float vv = (dd == 0) ? vq[bb].x : (dd == 1) ? vq[bb].y
                             : (dd == 2) ? vq[bb].z : vq[bb].w;
                    out[ln][bb] += vv * pd;
                }
            }
        }
    }

    // softmax over n (per b): local 4 + cross-lane bits 0..4 (bg bit fixed)
    float cv[4][8];
#pragma unroll
    for (int bb = 0; bb < 8; ++bb) {
        float m = fmaxf(fmaxf(out[0][bb], out[1][bb]),
                        fmaxf(out[2][bb], out[3][bb]));
        m = fmaxf(m, __shfl_xor(m, 1));
        m = fmaxf(m, __shfl_xor(m, 2));
        m = fmaxf(m, __shfl_xor(m, 4));
        m = fmaxf(m, __shfl_xor(m, 8));
        m = fmaxf(m, __shfl_xor(m, 16));
        float e0 = __expf(out[0][bb] - m);
        float e1 = __expf(out[1][bb] - m);
        float e2 = __expf(out[2][bb] - m);
        float e3 = __expf(out[3][bb] - m);
        float ss = e0 + e1 + e2 + e3;
        ss += __shfl_xor(ss, 1);
        ss += __shfl_xor(ss, 2);
        ss += __shfl_xor(ss, 4);
        ss += __shfl_xor(ss, 8);
        ss += __shfl_xor(ss, 16);
        float inv = 1.f / ss;
        cv[0][bb] = e0 * inv;
        cv[1][bb] = e1 * inv;
        cv[2][bb] = e2 * inv;
        cv[3][bb] = e3 * inv;
    }

    // store c_t[i][n][b]: 8 consecutive b per thread -> 2 float4
#pragma unroll
    for (int ln = 0; ln < 4; ++ln) {
        const int n = ng + 32 * ln;
        float* cp = c_t + ((size_t)i * N2_ + n) * 64 + b0;
        *(float4*)cp       = make_float4(cv[ln][0], cv[ln][1], cv[ln][2], cv[ln][3]);
        *(float4*)(cp + 4) = make_float4(cv[ln][4], cv[ln][5], cv[ln][6], cv[ln][7]);
    }
}

// ---------------------------------------------------------------------------
// K3C (MFMA): s1p[isp][b][n][d] = sum_{i in chunk, p} W[i,n,d,p]*c[b,i,n]*x[b,i,p]
// Mirror of k1, wave-per-n (A-split once per wave per i-block), B = c*x split.
// c_t[i][n][b] quad-loads are coalesced 64B lines.
// ---------------------------------------------------------------------------
__global__ __launch_bounds__(256) void k3c_s1_mfma(const float* __restrict__ x,
                                                   const float* __restrict__ W,
                                                   const float* __restrict__ c_t,
                                                   float* __restrict__ s1p)
{
    const int tid   = threadIdx.x;
    const int lane  = tid & 63;
    const int wv    = tid >> 6;
    const int col   = lane & 15;
    const int quad  = lane >> 4;
    const int n     = blockIdx.x * 4 + wv;
    const int isp   = blockIdx.y;
    const int ibase = isp * CHUNK;

    f32x4 acc[4];
#pragma unroll
    for (int bt = 0; bt < 4; ++bt) acc[bt] = (f32x4){0.f, 0.f, 0.f, 0.f};

    for (int ib = 0; ib < NIB; ++ib) {
        const int iq = ibase + ib * 4 + quad;
        const float* wp = W + ((size_t)iq * N2_ + n) * (D_ * P_) + col * P_;
        float4 wa = *(const float4*)wp;
        float4 wb = *(const float4*)(wp + 4);
        bf16x8 ahi, alo;
        split_frag(wa, wb, ahi, alo);
#pragma unroll
        for (int bt = 0; bt < 4; ++bt) {
            const int b = bt * 16 + col;
            const float* xp = x + ((size_t)b * N1_ + iq) * P_;
            float4 xa = *(const float4*)xp;
            float4 xb = *(const float4*)(xp + 4);
            float c = c_t[((size_t)iq * N2_ + n) * 64 + b];
            float4 ya = make_float4(xa.x * c, xa.y * c, xa.z * c, xa.w * c);
            float4 yb = make_float4(xb.x * c, xb.y * c, xb.z * c, xb.w * c);
            bf16x8 bhi, blo;
            split_frag(ya, yb, bhi, blo);
            acc[bt] = __builtin_amdgcn_mfma_f32_16x16x32_bf16(ahi, bhi, acc[bt], 0, 0, 0);
            acc[bt] = __builtin_amdgcn_mfma_f32_16x16x32_bf16(ahi, blo, acc[bt], 0, 0, 0);
            acc[bt] = __builtin_amdgcn_mfma_f32_16x16x32_bf16(alo, bhi, acc[bt], 0, 0, 0);
        }
    }
#pragma unroll
    for (int bt = 0; bt < 4; ++bt) {
        const int b = bt * 16 + col;
        float4 v = make_float4(acc[bt][0], acc[bt][1], acc[bt][2], acc[bt][3]);
        *(float4*)(s1p + (size_t)isp * (B_ * N2_ * D_) + (size_t)b * (N2_ * D_)
                   + n * D_ + quad * 4) = v;
    }
}

// ---------------------------------------------------------------------------
extern "C" void kernel_launch(void* const* d_in, const int* in_sizes, int n_in,
                              void* d_out, int out_size, void* d_ws, size_t ws_size,
                              hipStream_t stream)
{
    const float* x = (const float*)d_in[0];   // [64,1152,8]
    const float* W = (const float*)d_in[1];   // [1152,128,16,8]
    float* out = (float*)d_out;               // [64,128,16]

    float* s_part = (float*)d_ws;                               // 24*131072 floats
    float* v0     = s_part + (size_t)NSPLIT * B_ * N2_ * D_;    // 131072 floats
    float* c_t    = v0 + B_ * N2_ * D_;                         // 9437184 floats (c transposed [i][n][b])

    k1_s0_mfma  <<<dim3(32, NSPLIT), 256, 0, stream>>>(x, W, s_part);
    k2_squash   <<<512,              256, 0, stream>>>(s_part, v0, 1.f / 128.f, NSPLIT);
    k3ab        <<<N1_,              256, 0, stream>>>(x, W, v0, c_t);
    k3c_s1_mfma <<<dim3(32, NSPLIT), 256, 0, stream>>>(x, W, c_t, s_part);
    k2_squash   <<<512,              256, 0, stream>>>(s_part, out, 1.f, NSPLIT);
}

// Round 7
// 243.869 us; speedup vs baseline: 1.0962x; 1.0962x over previous
//
#include <hip/hip_runtime.h>
#include <math.h>

// dims
#define B_   64
#define N1_  1152
#define P_   8
#define N2_  128
#define D_   16

#define NSPLIT 24                      // i-splits for k1/k3c partials
#define CHUNK  (N1_ / NSPLIT)          // 48 i per chunk
#define NIB    (CHUNK / 4)             // 12 i-blocks of 4

typedef __attribute__((ext_vector_type(8))) short bf16x8;
typedef __attribute__((ext_vector_type(4))) float f32x4;

// split 8 fp32 into hi/lo bf16 fragments (hi = truncate, lo = bf16(w - hi))
__device__ inline void split_frag(float4 a0, float4 a1, bf16x8& hi, bf16x8& lo)
{
    float w[8] = {a0.x, a0.y, a0.z, a0.w, a1.x, a1.y, a1.z, a1.w};
#pragma unroll
    for (int j = 0; j < 8; ++j) {
        unsigned ub = __float_as_uint(w[j]);
        hi[j] = (short)(ub >> 16);
        float hif = __uint_as_float(ub & 0xffff0000u);
        float r = w[j] - hif;
        lo[j] = (short)(__float_as_uint(r) >> 16);
    }
}

// ---------------------------------------------------------------------------
// K1 (MFMA, validated r4): s0p[isp][b][n][d] = sum_{i in chunk, p} W[i,n,d,p]*x[b,i,p]
// ---------------------------------------------------------------------------
__global__ __launch_bounds__(256) void k1_s0_mfma(const float* __restrict__ x,
                                                  const float* __restrict__ W,
                                                  float* __restrict__ s0p)
{
    const int tid   = threadIdx.x;
    const int lane  = tid & 63;
    const int wv    = tid >> 6;
    const int col   = lane & 15;
    const int quad  = lane >> 4;
    const int b     = wv * 16 + col;
    const int nbase = blockIdx.x * 4;
    const int isp   = blockIdx.y;
    const int ibase = isp * CHUNK;

    f32x4 acc[4];
#pragma unroll
    for (int nn = 0; nn < 4; ++nn) acc[nn] = (f32x4){0.f, 0.f, 0.f, 0.f};

    const float* xlane = x + ((size_t)b * N1_ + ibase + quad) * P_;

    for (int ib = 0; ib < NIB; ++ib) {
        const int i0 = ibase + ib * 4;
        float4 xa = *(const float4*)(xlane);
        float4 xb = *(const float4*)(xlane + 4);
        xlane += 4 * P_;
        bf16x8 bhi, blo;
        split_frag(xa, xb, bhi, blo);
#pragma unroll
        for (int nn = 0; nn < 4; ++nn) {
            const float* wp = W + (((size_t)(i0 + quad) * N2_ + nbase + nn) * D_ + col) * P_;
            float4 wa = *(const float4*)wp;
            float4 wb = *(const float4*)(wp + 4);
            bf16x8 ahi, alo;
            split_frag(wa, wb, ahi, alo);
            acc[nn] = __builtin_amdgcn_mfma_f32_16x16x32_bf16(ahi, bhi, acc[nn], 0, 0, 0);
            acc[nn] = __builtin_amdgcn_mfma_f32_16x16x32_bf16(ahi, blo, acc[nn], 0, 0, 0);
            acc[nn] = __builtin_amdgcn_mfma_f32_16x16x32_bf16(alo, bhi, acc[nn], 0, 0, 0);
        }
    }
#pragma unroll
    for (int nn = 0; nn < 4; ++nn) {
        float4 v = make_float4(acc[nn][0], acc[nn][1], acc[nn][2], acc[nn][3]);
        *(float4*)(s0p + (size_t)isp * (B_ * N2_ * D_) + (size_t)b * (N2_ * D_)
                   + (nbase + nn) * D_ + quad * 4) = v;
    }
}

// ---------------------------------------------------------------------------
// K2/K4: reduce nsplit partials, scale, squash over d (16), write v.
// ---------------------------------------------------------------------------
__global__ __launch_bounds__(256) void k2_squash(const float* __restrict__ spart,
                                                 float* __restrict__ vout,
                                                 float scale, int nsplit)
{
    int idx = blockIdx.x * 256 + threadIdx.x;   // 0 .. 131071
    float s = 0.f;
    for (int sp = 0; sp < nsplit; ++sp)
        s += spart[(size_t)sp * (B_ * N2_ * D_) + idx];
    s *= scale;
    float sq = s * s;
    sq += __shfl_xor(sq, 1);
    sq += __shfl_xor(sq, 2);
    sq += __shfl_xor(sq, 4);
    sq += __shfl_xor(sq, 8);
    float norm = sqrtf(sq + 1.1920929e-7f);
    vout[idx] = (sq / (1.f + sq)) * (s / norm);
}

// ---------------------------------------------------------------------------
// K3A (MFMA): raw_t[i][n][b] = sum_d v0[b,n,d] * (sum_p W[i,n,d,p]*x[b,i,p])
//  = sum_p x[b,i,p] * Y[(i_sub,p), b],  Y = W_slice . v0_n  (GEMM over d)
// MFMA 16x16x32: M = (2 i x 8 p), K = d (16 real, upper 16 zero), N = b-tile.
// A-lane (m=lane&15 -> i_sub=m>>3, p=m&7; quad<2): W[i0+i_sub, n, d=quad*8+j, p]
// B-lane (col=b, quad<2): v0[b, n, d=quad*8+j] (contiguous f4x2) - hoisted &
//   split ONCE per block (i-invariant).
// Epilogue: D row = quad*4+reg = i_sub*8 + phalf*4 + reg; dot 4 with
//   x[b, i, phalf*4..], shfl_xor(16) combines p-halves; quads 0/2 store.
// grid (128 n, 9 i-chunks of 128); block 4 waves, wave handles i2 = wv+4k.
// No LDS, no barriers.
// ---------------------------------------------------------------------------
__global__ __launch_bounds__(256) void k3a_mfma(const float* __restrict__ x,
                                                const float* __restrict__ W,
                                                const float* __restrict__ v0,
                                                float* __restrict__ raw_t)
{
    const int tid   = threadIdx.x;
    const int lane  = tid & 63;
    const int wv    = tid >> 6;
    const int col   = lane & 15;
    const int quad  = lane >> 4;
    const int isub  = col >> 3;
    const int p     = col & 7;
    const int n     = blockIdx.x;
    const int ichunk = blockIdx.y * 128;

    // B fragments: v0 for 4 b-tiles, split once (quads 2,3 hold zeros)
    bf16x8 vhi[4], vlo[4];
#pragma unroll
    for (int bt = 0; bt < 4; ++bt) {
        float4 qa = make_float4(0.f, 0.f, 0.f, 0.f), qb = qa;
        if (quad < 2) {
            const float* vp = v0 + (size_t)(bt * 16 + col) * (N2_ * D_) + n * D_ + quad * 8;
            qa = *(const float4*)vp;
            qb = *(const float4*)(vp + 4);
        }
        split_frag(qa, qb, vhi[bt], vlo[bt]);
    }

    for (int t2 = wv; t2 < 64; t2 += 4) {
        const int i0 = ichunk + t2 * 2;
        // A fragment: W[i0+isub, n, d=quad*8+j, p], 8 dwords stride 32 B
        float4 wa = make_float4(0.f, 0.f, 0.f, 0.f), wb = wa;
        if (quad < 2) {
            const float* wp = W + ((size_t)(i0 + isub) * N2_ + n) * (D_ * P_) + quad * 64 + p;
            wa.x = wp[0];  wa.y = wp[8];  wa.z = wp[16]; wa.w = wp[24];
            wb.x = wp[32]; wb.y = wp[40]; wb.z = wp[48]; wb.w = wp[56];
        }
        bf16x8 ahi, alo;
        split_frag(wa, wb, ahi, alo);

        // epilogue x preload (per-lane: b=bt*16+col, i=i0+(quad>>1), p-half=quad&1)
        const int ie = i0 + (quad >> 1);
        const int ph = quad & 1;
        float4 x4[4];
#pragma unroll
        for (int bt = 0; bt < 4; ++bt)
            x4[bt] = *(const float4*)(x + ((size_t)(bt * 16 + col) * N1_ + ie) * P_ + ph * 4);

        f32x4 acc[4];
#pragma unroll
        for (int bt = 0; bt < 4; ++bt) acc[bt] = (f32x4){0.f, 0.f, 0.f, 0.f};
#pragma unroll
        for (int bt = 0; bt < 4; ++bt) {
            acc[bt] = __builtin_amdgcn_mfma_f32_16x16x32_bf16(ahi, vhi[bt], acc[bt], 0, 0, 0);
            acc[bt] = __builtin_amdgcn_mfma_f32_16x16x32_bf16(ahi, vlo[bt], acc[bt], 0, 0, 0);
            acc[bt] = __builtin_amdgcn_mfma_f32_16x16x32_bf16(alo, vhi[bt], acc[bt], 0, 0, 0);
        }
#pragma unroll
        for (int bt = 0; bt < 4; ++bt) {
            float r = acc[bt][0] * x4[bt].x + acc[bt][1] * x4[bt].y
                    + acc[bt][2] * x4[bt].z + acc[bt][3] * x4[bt].w;
            r += __shfl_xor(r, 16);
            if ((quad & 1) == 0)
                raw_t[(size_t)ie * (N2_ * 64) + n * 64 + bt * 16 + col] = r;
        }
    }
}

// ---------------------------------------------------------------------------
// K3B_T: in-place softmax over n on raw_t[i][n][b] -> c_t[i][n][b].
// block per i; thread (b=t&63, ng=t>>6) owns n = ng*32..+31 (regs).
// All global accesses are 256-B coalesced (b contiguous). In-place safe:
// each thread reads its 32 values into regs before any write, and no other
// thread touches its (i, n-range, b) elements.
// ---------------------------------------------------------------------------
__global__ __launch_bounds__(256) void k3b_t(float* __restrict__ rawc)
{
    const int i  = blockIdx.x;
    const int t  = threadIdx.x;
    const int b  = t & 63;
    const int ng = t >> 6;
    float* base = rawc + (size_t)i * (N2_ * 64) + b;

    float v[32];
    float m = -1e30f;
#pragma unroll
    for (int k = 0; k < 32; ++k) {
        v[k] = base[(ng * 32 + k) * 64];
        m = fmaxf(m, v[k]);
    }
    __shared__ float red[4][64];
    red[ng][b] = m;
    __syncthreads();
    m = fmaxf(fmaxf(red[0][b], red[1][b]), fmaxf(red[2][b], red[3][b]));
    float s = 0.f;
#pragma unroll
    for (int k = 0; k < 32; ++k) { v[k] = __expf(v[k] - m); s += v[k]; }
    __syncthreads();
    red[ng][b] = s;
    __syncthreads();
    s = red[0][b] + red[1][b] + red[2][b] + red[3][b];
    float inv = 1.f / s;
#pragma unroll
    for (int k = 0; k < 32; ++k)
        base[(ng * 32 + k) * 64] = v[k] * inv;
}

// ---------------------------------------------------------------------------
// K3C (MFMA, r6): s1p[isp][b][n][d] = sum_{i,p} W[i,n,d,p]*c[b,i,n]*x[b,i,p]
// ---------------------------------------------------------------------------
__global__ __launch_bounds__(256) void k3c_s1_mfma(const float* __restrict__ x,
                                                   const float* __restrict__ W,
                                                   const float* __restrict__ c_t,
                                                   float* __restrict__ s1p)
{
    const int tid   = threadIdx.x;
    const int lane  = tid & 63;
    const int wv    = tid >> 6;
    const int col   = lane & 15;
    const int quad  = lane >> 4;
    const int n     = blockIdx.x * 4 + wv;
    const int isp   = blockIdx.y;
    const int ibase = isp * CHUNK;

    f32x4 acc[4];
#pragma unroll
    for (int bt = 0; bt < 4; ++bt) acc[bt] = (f32x4){0.f, 0.f, 0.f, 0.f};

    for (int ib = 0; ib < NIB; ++ib) {
        const int iq = ibase + ib * 4 + quad;
        const float* wp = W + ((size_t)iq * N2_ + n) * (D_ * P_) + col * P_;
        float4 wa = *(const float4*)wp;
        float4 wb = *(const float4*)(wp + 4);
        bf16x8 ahi, alo;
        split_frag(wa, wb, ahi, alo);
#pragma unroll
        for (int bt = 0; bt < 4; ++bt) {
            const int b = bt * 16 + col;
            const float* xp = x + ((size_t)b * N1_ + iq) * P_;
            float4 xa = *(const float4*)xp;
            float4 xb = *(const float4*)(xp + 4);
            float c = c_t[((size_t)iq * N2_ + n) * 64 + b];
            float4 ya = make_float4(xa.x * c, xa.y * c, xa.z * c, xa.w * c);
            float4 yb = make_float4(xb.x * c, xb.y * c, xb.z * c, xb.w * c);
            bf16x8 bhi, blo;
            split_frag(ya, yb, bhi, blo);
            acc[bt] = __builtin_amdgcn_mfma_f32_16x16x32_bf16(ahi, bhi, acc[bt], 0, 0, 0);
            acc[bt] = __builtin_amdgcn_mfma_f32_16x16x32_bf16(ahi, blo, acc[bt], 0, 0, 0);
            acc[bt] = __builtin_amdgcn_mfma_f32_16x16x32_bf16(alo, bhi, acc[bt], 0, 0, 0);
        }
    }
#pragma unroll
    for (int bt = 0; bt < 4; ++bt) {
        const int b = bt * 16 + col;
        float4 v = make_float4(acc[bt][0], acc[bt][1], acc[bt][2], acc[bt][3]);
        *(float4*)(s1p + (size_t)isp * (B_ * N2_ * D_) + (size_t)b * (N2_ * D_)
                   + n * D_ + quad * 4) = v;
    }
}

// ---------------------------------------------------------------------------
extern "C" void kernel_launch(void* const* d_in, const int* in_sizes, int n_in,
                              void* d_out, int out_size, void* d_ws, size_t ws_size,
                              hipStream_t stream)
{
    const float* x = (const float*)d_in[0];   // [64,1152,8]
    const float* W = (const float*)d_in[1];   // [1152,128,16,8]
    float* out = (float*)d_out;               // [64,128,16]

    float* s_part = (float*)d_ws;                               // 24*131072 floats
    float* v0     = s_part + (size_t)NSPLIT * B_ * N2_ * D_;    // 131072 floats
    float* c_t    = v0 + B_ * N2_ * D_;                         // 9437184 floats: raw_t then (in-place) c_t, layout [i][n][b]

    k1_s0_mfma  <<<dim3(32, NSPLIT), 256, 0, stream>>>(x, W, s_part);
    k2_squash   <<<512,              256, 0, stream>>>(s_part, v0, 1.f / 128.f, NSPLIT);
    k3a_mfma    <<<dim3(128, 9),     256, 0, stream>>>(x, W, v0, c_t);
    k3b_t       <<<N1_,              256, 0, stream>>>(c_t);
    k3c_s1_mfma <<<dim3(32, NSPLIT), 256, 0, stream>>>(x, W, c_t, s_part);
    k2_squash   <<<512,              256, 0, stream>>>(s_part, out, 1.f, NSPLIT);
}